// Round 1
// baseline (2084.302 us; speedup 1.0000x reference)
//
#include <hip/hip_runtime.h>
#include <math.h>

#define BB 4096
#define TT 5
#define KK 4
#define NLANES 12
#define GH 64
#define GO 32
#define NHEADS 4
#define GAT_TOT 256
#define SAGE_H 64
#define GRU_H 32

// ---------------------------------------------------------------------------
// Kernel A: per (b,t) block computes GAT for self + 4 neighbors, then the
// masked-mean aggregation and the central-node GraphSAGE row.
// Writes hsage[B,T,64] and (for t==T-1) self_emb_last[B,256].
// ---------------------------------------------------------------------------
__global__ __launch_bounds__(256) void gat_sage_kernel(
    const float* __restrict__ selfF, const float* __restrict__ nbF,
    const float* __restrict__ mask,
    const float* __restrict__ projW, const float* __restrict__ projB,
    const float* __restrict__ projG, const float* __restrict__ projBt,
    const float* __restrict__ coopW, const float* __restrict__ coopSrc, const float* __restrict__ coopDst,
    const float* __restrict__ confW, const float* __restrict__ confSrc, const float* __restrict__ confDst,
    const float* __restrict__ sageW, const float* __restrict__ sageB,
    float* __restrict__ hsage, float* __restrict__ embLast)
{
    __shared__ float s_x[48];
    __shared__ float s_h[NLANES * GH];           // 768
    __shared__ float s_Wh[8 * NLANES * GO];      // 3072 (2 gats x 4 heads)
    __shared__ float s_sd[2 * 8 * NLANES];       // src[96], dst[96]
    __shared__ float s_att[8 * NLANES * NLANES]; // 1152
    __shared__ float s_pool[5 * GAT_TOT];        // 1280
    __shared__ float s_mean[NLANES], s_rstd[NLANES];
    __shared__ float s_in[2 * GAT_TOT];          // sage input 512

    const int bid = blockIdx.x;          // b*T + t
    const int b = bid / TT, t = bid % TT;
    const int tid = threadIdx.x;

    for (int inst = 0; inst < 1 + KK; ++inst) {
        const float* xp = (inst == 0)
            ? (selfF + (size_t)bid * 48)
            : (nbF + (size_t)((b * KK + (inst - 1)) * TT + t) * 48);
        if (tid < 48) s_x[tid] = xp[tid];
        __syncthreads();

        // proj: h0[lane, f] = x[lane,:4] @ projW + b
        for (int idx = tid; idx < NLANES * GH; idx += 256) {
            int lane = idx >> 6, f = idx & 63;
            float v = projB[f];
            #pragma unroll
            for (int c = 0; c < 4; ++c) v += s_x[lane * 4 + c] * projW[c * GH + f];
            s_h[idx] = v;
        }
        __syncthreads();

        // per-lane LayerNorm stats (two-pass)
        if (tid < NLANES) {
            float m = 0.f;
            for (int f = 0; f < GH; ++f) m += s_h[tid * GH + f];
            m *= (1.f / GH);
            float var = 0.f;
            for (int f = 0; f < GH; ++f) { float d = s_h[tid * GH + f] - m; var += d * d; }
            var *= (1.f / GH);
            s_mean[tid] = m;
            s_rstd[tid] = rsqrtf(var + 1e-5f);
        }
        __syncthreads();

        // apply LN + relu
        for (int idx = tid; idx < NLANES * GH; idx += 256) {
            int lane = idx >> 6, f = idx & 63;
            float v = (s_h[idx] - s_mean[lane]) * s_rstd[lane] * projG[f] + projBt[f];
            s_h[idx] = fmaxf(v, 0.f);
        }
        __syncthreads();

        // Wh: thread owns (gh, o); registers reuse each weight across 12 lanes
        {
            int gh = tid >> 5, o = tid & 31;   // gh 0..7: g=gh>>2, head=gh&3
            int g = gh >> 2, hh = gh & 3;
            const float* W = (g ? confW : coopW) + hh * GH * GO + o;
            float acc[NLANES];
            #pragma unroll
            for (int n = 0; n < NLANES; ++n) acc[n] = 0.f;
            for (int f = 0; f < GH; ++f) {
                float w = W[f * GO];
                #pragma unroll
                for (int n = 0; n < NLANES; ++n) acc[n] += s_h[n * GH + f] * w;
            }
            #pragma unroll
            for (int n = 0; n < NLANES; ++n) s_Wh[(gh * NLANES + n) * GO + o] = acc[n];
        }
        __syncthreads();

        // attention src/dst scalars
        if (tid < 192) {
            int half = tid / 96;      // 0=src 1=dst
            int r = tid % 96;         // gh*12 + n
            int gh = r / NLANES;
            int g = gh >> 2, hh = gh & 3;
            const float* a = (g ? (half ? confDst : confSrc)
                                : (half ? coopDst : coopSrc)) + hh * GO;
            const float* wh = &s_Wh[r * GO];
            float v = 0.f;
            for (int o = 0; o < GO; ++o) v += wh[o] * a[o];
            s_sd[tid] = v;
        }
        __syncthreads();

        // masked softmax rows
        if (tid < 96) {
            int gh = tid / NLANES;
            int n = tid % NLANES;
            int g = gh >> 2;
            int an = n / 3;
            float sn = s_sd[tid];
            float e[NLANES];
            float mx = -1e30f;
            #pragma unroll
            for (int m2 = 0; m2 < NLANES; ++m2) {
                int am = m2 / 3;
                bool valid = (g == 0) ? (am == an) : (am != an || m2 == n);
                if (valid) {
                    float ev = sn + s_sd[96 + gh * NLANES + m2];
                    ev = ev > 0.f ? ev : 0.2f * ev;   // leaky_relu 0.2
                    e[m2] = ev;
                    mx = fmaxf(mx, ev);
                } else e[m2] = -1e30f;
            }
            float sum = 0.f;
            #pragma unroll
            for (int m2 = 0; m2 < NLANES; ++m2) {
                float ex = (e[m2] > -1e29f) ? expf(e[m2] - mx) : 0.f;
                e[m2] = ex; sum += ex;
            }
            float inv = 1.f / sum;
            #pragma unroll
            for (int m2 = 0; m2 < NLANES; ++m2) s_att[tid * NLANES + m2] = e[m2] * inv;
        }
        __syncthreads();

        // out = att @ Wh, elu, mean over lanes -> pooled[tid] (feature = tid)
        {
            int gh = tid >> 5;  // g*4+hh; o = tid & 31; feature f = tid
            int o = tid & 31;
            float acc = 0.f;
            #pragma unroll
            for (int n = 0; n < NLANES; ++n) {
                const float* arow = &s_att[(gh * NLANES + n) * NLANES];
                float v = 0.f;
                #pragma unroll
                for (int m2 = 0; m2 < NLANES; ++m2)
                    v += arow[m2] * s_Wh[(gh * NLANES + m2) * GO + o];
                v = v > 0.f ? v : expm1f(v);   // elu
                acc += v;
            }
            s_pool[inst * GAT_TOT + tid] = acc * (1.f / 12.f);
        }
        __syncthreads();
    }

    // agg (masked mean of neighbors) + concat -> sage input
    {
        float m0 = mask[b * KK + 0], m1 = mask[b * KK + 1];
        float m2 = mask[b * KK + 2], m3 = mask[b * KK + 3];
        float inv = 1.f / fmaxf(m0 + m1 + m2 + m3, 1.f);
        s_in[tid] = s_pool[tid];
        s_in[GAT_TOT + tid] = (m0 * s_pool[1 * GAT_TOT + tid] + m1 * s_pool[2 * GAT_TOT + tid]
                             + m2 * s_pool[3 * GAT_TOT + tid] + m3 * s_pool[4 * GAT_TOT + tid]) * inv;
    }
    __syncthreads();

    // central-node GraphSAGE row: relu(concat @ sage_W + b)
    if (tid < SAGE_H) {
        float v = sageB[tid];
        for (int c = 0; c < 2 * GAT_TOT; ++c) v += s_in[c] * sageW[c * SAGE_H + tid];
        hsage[(size_t)bid * SAGE_H + tid] = fmaxf(v, 0.f);
    }
    if (t == TT - 1) embLast[(size_t)b * GAT_TOT + tid] = s_pool[tid];
}

// ---------------------------------------------------------------------------
// Kernel B: per-b block. Bidirectional GRU over T=5 (threads 0..63: dir*32+j),
// then both MLP heads (policy logits[8] + value[1]).
// ---------------------------------------------------------------------------
__global__ __launch_bounds__(128) void gru_head_kernel(
    const float* __restrict__ hsage, const float* __restrict__ embLast,
    const float* __restrict__ gfWx, const float* __restrict__ gfWh,
    const float* __restrict__ gfbx, const float* __restrict__ gfbh,
    const float* __restrict__ gbWx, const float* __restrict__ gbWh,
    const float* __restrict__ gbbx, const float* __restrict__ gbbh,
    const float* __restrict__ pW1, const float* __restrict__ pb1,
    const float* __restrict__ pg1, const float* __restrict__ pbt1,
    const float* __restrict__ pW2, const float* __restrict__ pb2,
    const float* __restrict__ pg2, const float* __restrict__ pbt2,
    const float* __restrict__ pWo, const float* __restrict__ pbo,
    const float* __restrict__ vW1, const float* __restrict__ vb1,
    const float* __restrict__ vg1, const float* __restrict__ vbt1,
    const float* __restrict__ vW2, const float* __restrict__ vb2,
    const float* __restrict__ vg2, const float* __restrict__ vbt2,
    const float* __restrict__ vWo, const float* __restrict__ vbo,
    float* __restrict__ dout)
{
    __shared__ float s_seq[TT * SAGE_H];   // 320
    __shared__ float s_h[2 * GRU_H];       // 64 (fwd | bwd)
    __shared__ float s_joint[320];
    __shared__ float s_h1[128];
    __shared__ float s_h2[64];
    __shared__ float s_red[2];

    const int b = blockIdx.x, tid = threadIdx.x;

    for (int idx = tid; idx < TT * SAGE_H; idx += 128)
        s_seq[idx] = hsage[(size_t)b * TT * SAGE_H + idx];
    if (tid < 64) s_h[tid] = 0.f;
    __syncthreads();

    for (int s = 0; s < TT; ++s) {
        float hnew = 0.f;
        if (tid < 64) {
            int dir = tid >> 5, j = tid & 31;
            int t = dir ? (TT - 1 - s) : s;
            const float* x  = &s_seq[t * SAGE_H];
            const float* h  = &s_h[dir * GRU_H];
            const float* Wx = dir ? gbWx : gfWx;
            const float* Wh = dir ? gbWh : gfWh;
            const float* bx = dir ? gbbx : gfbx;
            const float* bh = dir ? gbbh : gfbh;
            float xr = bx[j], xz = bx[32 + j], xn = bx[64 + j];
            for (int f = 0; f < SAGE_H; ++f) {
                float xv = x[f];
                xr += xv * Wx[f * 96 + j];
                xz += xv * Wx[f * 96 + 32 + j];
                xn += xv * Wx[f * 96 + 64 + j];
            }
            float hr = bh[j], hz = bh[32 + j], hn = bh[64 + j];
            for (int k2 = 0; k2 < GRU_H; ++k2) {
                float hv = h[k2];
                hr += hv * Wh[k2 * 96 + j];
                hz += hv * Wh[k2 * 96 + 32 + j];
                hn += hv * Wh[k2 * 96 + 64 + j];
            }
            float r = 1.f / (1.f + expf(-(xr + hr)));
            float z = 1.f / (1.f + expf(-(xz + hz)));
            float nn = tanhf(xn + r * hn);
            hnew = (1.f - z) * nn + z * h[j];
        }
        __syncthreads();
        if (tid < 64) s_h[tid] = hnew;
        __syncthreads();
    }

    // joint = [self_emb_last(256) | net(64)]
    for (int idx = tid; idx < GAT_TOT; idx += 128)
        s_joint[idx] = embLast[(size_t)b * GAT_TOT + idx];
    if (tid < 64) s_joint[GAT_TOT + tid] = s_h[tid];
    __syncthreads();

    for (int hd = 0; hd < 2; ++hd) {
        const float* W1 = hd ? vW1 : pW1;  const float* b1 = hd ? vb1 : pb1;
        const float* g1 = hd ? vg1 : pg1;  const float* bt1 = hd ? vbt1 : pbt1;
        const float* W2 = hd ? vW2 : pW2;  const float* b2 = hd ? vb2 : pb2;
        const float* g2 = hd ? vg2 : pg2;  const float* bt2 = hd ? vbt2 : pbt2;
        const float* Wo = hd ? vWo : pWo;  const float* bo = hd ? vbo : pbo;

        float v = b1[tid];
        for (int c = 0; c < 320; ++c) v += s_joint[c] * W1[c * 128 + tid];
        s_h1[tid] = v;
        __syncthreads();
        if (tid == 0) {
            float m = 0.f; for (int c = 0; c < 128; ++c) m += s_h1[c]; m *= (1.f / 128.f);
            float var = 0.f; for (int c = 0; c < 128; ++c) { float d = s_h1[c] - m; var += d * d; }
            var *= (1.f / 128.f);
            s_red[0] = m; s_red[1] = rsqrtf(var + 1e-5f);
        }
        __syncthreads();
        s_h1[tid] = fmaxf((s_h1[tid] - s_red[0]) * s_red[1] * g1[tid] + bt1[tid], 0.f);
        __syncthreads();

        if (tid < 64) {
            float v2 = b2[tid];
            for (int c = 0; c < 128; ++c) v2 += s_h1[c] * W2[c * 64 + tid];
            s_h2[tid] = v2;
        }
        __syncthreads();
        if (tid == 0) {
            float m = 0.f; for (int c = 0; c < 64; ++c) m += s_h2[c]; m *= (1.f / 64.f);
            float var = 0.f; for (int c = 0; c < 64; ++c) { float d = s_h2[c] - m; var += d * d; }
            var *= (1.f / 64.f);
            s_red[0] = m; s_red[1] = rsqrtf(var + 1e-5f);
        }
        __syncthreads();
        if (tid < 64)
            s_h2[tid] = fmaxf((s_h2[tid] - s_red[0]) * s_red[1] * g2[tid] + bt2[tid], 0.f);
        __syncthreads();

        if (hd == 0) {
            if (tid < 8) {
                float v3 = bo[tid];
                for (int c = 0; c < 64; ++c) v3 += s_h2[c] * Wo[c * 8 + tid];
                dout[(size_t)b * 8 + tid] = v3;
            }
        } else {
            if (tid == 0) {
                float v3 = bo[0];
                for (int c = 0; c < 64; ++c) v3 += s_h2[c] * Wo[c];
                dout[(size_t)BB * 8 + b] = v3;
            }
        }
        __syncthreads();
    }
}

extern "C" void kernel_launch(void* const* d_in, const int* in_sizes, int n_in,
                              void* d_out, int out_size, void* d_ws, size_t ws_size,
                              hipStream_t stream) {
    (void)in_sizes; (void)n_in; (void)out_size; (void)ws_size;
    const float* selfF  = (const float*)d_in[0];
    const float* nbF    = (const float*)d_in[1];
    const float* mask   = (const float*)d_in[2];
    const float* projW  = (const float*)d_in[3];
    const float* projB  = (const float*)d_in[4];
    const float* projG  = (const float*)d_in[5];
    const float* projBt = (const float*)d_in[6];
    const float* coopW  = (const float*)d_in[7];
    const float* coopS  = (const float*)d_in[8];
    const float* coopD  = (const float*)d_in[9];
    const float* confW  = (const float*)d_in[10];
    const float* confS  = (const float*)d_in[11];
    const float* confD  = (const float*)d_in[12];
    const float* sageW  = (const float*)d_in[13];
    const float* sageB  = (const float*)d_in[14];
    const float* gfWx = (const float*)d_in[15];
    const float* gfWh = (const float*)d_in[16];
    const float* gfbx = (const float*)d_in[17];
    const float* gfbh = (const float*)d_in[18];
    const float* gbWx = (const float*)d_in[19];
    const float* gbWh = (const float*)d_in[20];
    const float* gbbx = (const float*)d_in[21];
    const float* gbbh = (const float*)d_in[22];
    const float* pW1  = (const float*)d_in[23];
    const float* pb1  = (const float*)d_in[24];
    const float* pg1  = (const float*)d_in[25];
    const float* pbt1 = (const float*)d_in[26];
    const float* pW2  = (const float*)d_in[27];
    const float* pb2  = (const float*)d_in[28];
    const float* pg2  = (const float*)d_in[29];
    const float* pbt2 = (const float*)d_in[30];
    const float* pWo  = (const float*)d_in[31];
    const float* pbo  = (const float*)d_in[32];
    const float* vW1  = (const float*)d_in[33];
    const float* vb1  = (const float*)d_in[34];
    const float* vg1  = (const float*)d_in[35];
    const float* vbt1 = (const float*)d_in[36];
    const float* vW2  = (const float*)d_in[37];
    const float* vb2  = (const float*)d_in[38];
    const float* vg2  = (const float*)d_in[39];
    const float* vbt2 = (const float*)d_in[40];
    const float* vWo  = (const float*)d_in[41];
    const float* vbo  = (const float*)d_in[42];

    float* hsage   = (float*)d_ws;                              // B*T*64
    float* embLast = hsage + (size_t)BB * TT * SAGE_H;          // B*256

    gat_sage_kernel<<<BB * TT, 256, 0, stream>>>(
        selfF, nbF, mask, projW, projB, projG, projBt,
        coopW, coopS, coopD, confW, confS, confD,
        sageW, sageB, hsage, embLast);

    gru_head_kernel<<<BB, 128, 0, stream>>>(
        hsage, embLast,
        gfWx, gfWh, gfbx, gfbh, gbWx, gbWh, gbbx, gbbh,
        pW1, pb1, pg1, pbt1, pW2, pb2, pg2, pbt2, pWo, pbo,
        vW1, vb1, vg1, vbt1, vW2, vb2, vg2, vbt2, vWo, vbo,
        (float*)d_out);
}